// Round 6
// baseline (843.829 us; speedup 1.0000x reference)
//
#include <hip/hip_runtime.h>
#include <hip/hip_bf16.h>
#include <hip/hip_fp16.h>

#define IN_FT 128
#define OUT_FT 64
#define BROWS 128          // rows per bucket (low 7 bits of row)
#define BCAP  2560         // slots per bucket: mean 2046 + ~11 sigma
#define PART_BLOCKS 256    // blocks in partition kernel

// ===========================================================================
// FC (main path): h = x @ W + b, h stored FP16 (halves gather traffic).
// fp32 accumulate on vector ALU — no fp32 MFMA on CDNA4.
// ===========================================================================
constexpr int ROWS_PER_BLOCK = 64;
constexpr int XS_STRIDE = 132;

__global__ __launch_bounds__(256) void gcn_fc_fp16_kernel(
    const float* __restrict__ x, const float* __restrict__ W,
    const float* __restrict__ b, __half* __restrict__ h, int N)
{
    __shared__ float Wl[IN_FT * OUT_FT];
    __shared__ float xs[ROWS_PER_BLOCK * XS_STRIDE];

    const int tid  = threadIdx.x;
    const int row0 = blockIdx.x * ROWS_PER_BLOCK;

    for (int i = tid; i < (IN_FT * OUT_FT) / 4; i += 256)
        reinterpret_cast<float4*>(Wl)[i] = reinterpret_cast<const float4*>(W)[i];

    for (int i = tid; i < (ROWS_PER_BLOCK * IN_FT) / 4; i += 256) {
        const int r  = i / (IN_FT / 4);
        const int c4 = i % (IN_FT / 4);
        float4 v = make_float4(0.f, 0.f, 0.f, 0.f);
        if (row0 + r < N)
            v = reinterpret_cast<const float4*>(x + (size_t)(row0 + r) * IN_FT)[c4];
        reinterpret_cast<float4*>(&xs[r * XS_STRIDE])[c4] = v;
    }
    __syncthreads();

    const int jg = tid & 15;
    const int rg = tid >> 4;

    const float4 bv = reinterpret_cast<const float4*>(b)[jg];
    float acc[4][4];
#pragma unroll
    for (int rr = 0; rr < 4; ++rr) {
        acc[rr][0] = bv.x; acc[rr][1] = bv.y; acc[rr][2] = bv.z; acc[rr][3] = bv.w;
    }

    for (int k0 = 0; k0 < IN_FT; k0 += 4) {
        float wf[4][4];
#pragma unroll
        for (int kk = 0; kk < 4; ++kk) {
            const float4 t = *reinterpret_cast<const float4*>(&Wl[(k0 + kk) * OUT_FT + 4 * jg]);
            wf[kk][0] = t.x; wf[kk][1] = t.y; wf[kk][2] = t.z; wf[kk][3] = t.w;
        }
#pragma unroll
        for (int rr = 0; rr < 4; ++rr) {
            const float4 xv = *reinterpret_cast<const float4*>(&xs[(4 * rg + rr) * XS_STRIDE + k0]);
            const float xk[4] = {xv.x, xv.y, xv.z, xv.w};
#pragma unroll
            for (int kk = 0; kk < 4; ++kk)
#pragma unroll
                for (int jj = 0; jj < 4; ++jj)
                    acc[rr][jj] += xk[kk] * wf[kk][jj];
        }
    }

#pragma unroll
    for (int rr = 0; rr < 4; ++rr) {
        const int r = row0 + 4 * rg + rr;
        if (r < N) {
            __half2 p0 = __floats2half2_rn(acc[rr][0], acc[rr][1]);
            __half2 p1 = __floats2half2_rn(acc[rr][2], acc[rr][3]);
            uint2 pk;
            pk.x = *reinterpret_cast<unsigned*>(&p0);
            pk.y = *reinterpret_cast<unsigned*>(&p1);
            *reinterpret_cast<uint2*>(&h[(size_t)r * OUT_FT + 4 * jg]) = pk;
        }
    }
}

// ===========================================================================
// Partition: bucket edges by row>>7. Two-pass LDS histogram per block:
//   pass A: count per bin; reserve span with ONE global atomic per (block,bin)
//   pass B: LDS-rank each edge, write packed {col | rowlow<<17, val}
// Global returning atomics: ~PART_BLOCKS*NB = 200K (vs 1.6M in old k_count).
// ===========================================================================
__global__ __launch_bounds__(256) void k_partition(
    const int* __restrict__ erow, const int* __restrict__ ecol,
    const float* __restrict__ eval_, int* __restrict__ gcur,
    int2* __restrict__ ebuf, int E, int NB)
{
    __shared__ int hist[1024];
    __shared__ int base[1024];

    const int tid = threadIdx.x;
    const int CH  = (E + PART_BLOCKS - 1) / PART_BLOCKS;
    const int e0  = blockIdx.x * CH;
    const int e1  = min(E, e0 + CH);

    for (int i = tid; i < NB; i += 256) hist[i] = 0;
    __syncthreads();

    // pass A: per-block histogram (LDS atomics, no return needed)
    for (int i = e0 + tid; i < e1; i += 256)
        atomicAdd(&hist[erow[i] >> 7], 1);
    __syncthreads();

    // reserve: one global returning atomic per nonzero bin
    for (int i = tid; i < NB; i += 256) {
        const int c = hist[i];
        base[i] = c ? atomicAdd(&gcur[i], c) : 0;
    }
    __syncthreads();
    for (int i = tid; i < NB; i += 256) hist[i] = 0;
    __syncthreads();

    // pass B: rank within (block,bin) via LDS returning atomic, scatter write
    for (int i = e0 + tid; i < e1; i += 256) {
        const int   r   = erow[i];
        const int   c   = ecol[i];
        const float v   = eval_[i];
        const int   bin = r >> 7;
        const int   lr  = atomicAdd(&hist[bin], 1);
        const int   slot = base[bin] + lr;
        if (slot < BCAP)   // statistically unreachable; memory-safety clamp
            ebuf[(size_t)bin * BCAP + slot] =
                make_int2(c | ((r & (BROWS - 1)) << 17), __float_as_int(v));
    }
}

// ===========================================================================
// Bucket gather: one block per bucket. 32KB LDS f32 accumulator
// (128 rows x 64 feat). Wave-per-edge, lane=feature, ds_add_f32 accumulate
// (lane&31 -> 2-way bank alias = free). PReLU fused in coalesced epilogue.
// ===========================================================================
__global__ __launch_bounds__(256) void k_bucket_gather(
    const __half* __restrict__ h, const int* __restrict__ gcur,
    const int2* __restrict__ ebuf, const float* __restrict__ alpha,
    float* __restrict__ out, int N)
{
    __shared__ float acc[BROWS * OUT_FT];   // 32 KB

    const int tid  = threadIdx.x;
    const int bin  = blockIdx.x;
    const int row0 = bin << 7;

    for (int i = tid; i < (BROWS * OUT_FT) / 4; i += 256)
        reinterpret_cast<float4*>(acc)[i] = make_float4(0.f, 0.f, 0.f, 0.f);
    __syncthreads();

    const int  cnt  = min(gcur[bin], BCAP);
    const int  lane = tid & 63;
    const int  wid  = tid >> 6;
    const int2* bp  = ebuf + (size_t)bin * BCAP;

    // 2 edges per iteration -> two independent h loads in flight
    int i = wid * 2;
    for (; i + 1 < cnt; i += 8) {
        const int2 e0 = bp[i];
        const int2 e1 = bp[i + 1];
        const int   c0 = e0.x & 0x1FFFF,          c1 = e1.x & 0x1FFFF;
        const int   r0 = (e0.x >> 17) & (BROWS-1), r1 = (e1.x >> 17) & (BROWS-1);
        const float v0 = __int_as_float(e0.y),    v1 = __int_as_float(e1.y);
        const float h0 = __half2float(h[(size_t)c0 * OUT_FT + lane]);
        const float h1 = __half2float(h[(size_t)c1 * OUT_FT + lane]);
        atomicAdd(&acc[r0 * OUT_FT + lane], v0 * h0);
        atomicAdd(&acc[r1 * OUT_FT + lane], v1 * h1);
    }
    if (i < cnt) {   // odd tail
        const int2 e = bp[i];
        const int   c = e.x & 0x1FFFF;
        const int   rl = (e.x >> 17) & (BROWS - 1);
        const float v  = __int_as_float(e.y);
        atomicAdd(&acc[rl * OUT_FT + lane],
                  v * __half2float(h[(size_t)c * OUT_FT + lane]));
    }
    __syncthreads();

    const float a = alpha[0];
    for (int k = tid; k < (BROWS * OUT_FT) / 4; k += 256) {
        const int r = row0 + (k >> 4);          // 16 float4 per row
        if (r < N) {
            float4 vv = reinterpret_cast<float4*>(acc)[k];
            vv.x = vv.x >= 0.f ? vv.x : a * vv.x;
            vv.y = vv.y >= 0.f ? vv.y : a * vv.y;
            vv.z = vv.z >= 0.f ? vv.z : a * vv.z;
            vv.w = vv.w >= 0.f ? vv.w : a * vv.w;
            reinterpret_cast<float4*>(&out[(size_t)r * OUT_FT])[k & 15] = vv;
        }
    }
}

// ===========================================================================
// Fallback path (ws too small / N too large for 17-bit col pack)
// ===========================================================================
__global__ __launch_bounds__(256) void gcn_fc_kernel(
    const float* __restrict__ x, const float* __restrict__ W,
    const float* __restrict__ b, float* __restrict__ h, int N)
{
    __shared__ float Wl[IN_FT * OUT_FT];
    __shared__ float xs[ROWS_PER_BLOCK * XS_STRIDE];

    const int tid  = threadIdx.x;
    const int row0 = blockIdx.x * ROWS_PER_BLOCK;

    for (int i = tid; i < (IN_FT * OUT_FT) / 4; i += 256)
        reinterpret_cast<float4*>(Wl)[i] = reinterpret_cast<const float4*>(W)[i];

    for (int i = tid; i < (ROWS_PER_BLOCK * IN_FT) / 4; i += 256) {
        const int r  = i / (IN_FT / 4);
        const int c4 = i % (IN_FT / 4);
        float4 v = make_float4(0.f, 0.f, 0.f, 0.f);
        if (row0 + r < N)
            v = reinterpret_cast<const float4*>(x + (size_t)(row0 + r) * IN_FT)[c4];
        reinterpret_cast<float4*>(&xs[r * XS_STRIDE])[c4] = v;
    }
    __syncthreads();

    const int jg = tid & 15;
    const int rg = tid >> 4;

    const float4 bv = reinterpret_cast<const float4*>(b)[jg];
    float acc[4][4];
#pragma unroll
    for (int rr = 0; rr < 4; ++rr) {
        acc[rr][0] = bv.x; acc[rr][1] = bv.y; acc[rr][2] = bv.z; acc[rr][3] = bv.w;
    }

    for (int k0 = 0; k0 < IN_FT; k0 += 4) {
        float wf[4][4];
#pragma unroll
        for (int kk = 0; kk < 4; ++kk) {
            const float4 t = *reinterpret_cast<const float4*>(&Wl[(k0 + kk) * OUT_FT + 4 * jg]);
            wf[kk][0] = t.x; wf[kk][1] = t.y; wf[kk][2] = t.z; wf[kk][3] = t.w;
        }
#pragma unroll
        for (int rr = 0; rr < 4; ++rr) {
            const float4 xv = *reinterpret_cast<const float4*>(&xs[(4 * rg + rr) * XS_STRIDE + k0]);
            const float xk[4] = {xv.x, xv.y, xv.z, xv.w};
#pragma unroll
            for (int kk = 0; kk < 4; ++kk)
#pragma unroll
                for (int jj = 0; jj < 4; ++jj)
                    acc[rr][jj] += xk[kk] * wf[kk][jj];
        }
    }

#pragma unroll
    for (int rr = 0; rr < 4; ++rr) {
        const int r = row0 + 4 * rg + rr;
        if (r < N)
            *reinterpret_cast<float4*>(&h[(size_t)r * OUT_FT + 4 * jg]) =
                make_float4(acc[rr][0], acc[rr][1], acc[rr][2], acc[rr][3]);
    }
}

__global__ __launch_bounds__(256) void gcn_scatter_kernel(
    const float* __restrict__ h, const int* __restrict__ erow,
    const int* __restrict__ ecol, const float* __restrict__ eval_,
    float* __restrict__ out, int E)
{
    const int t  = blockIdx.x * blockDim.x + threadIdx.x;
    const int e  = t >> 4;
    const int fg = (t & 15) * 4;
    if (e >= E) return;
    const int   col = ecol[e];
    const int   row = erow[e];
    const float v   = eval_[e];
    const float4 hv = *reinterpret_cast<const float4*>(&h[(size_t)col * OUT_FT + fg]);
    float* op = &out[(size_t)row * OUT_FT + fg];
    atomicAdd(op + 0, v * hv.x);
    atomicAdd(op + 1, v * hv.y);
    atomicAdd(op + 2, v * hv.z);
    atomicAdd(op + 3, v * hv.w);
}

__global__ __launch_bounds__(256) void gcn_prelu_kernel(
    float* __restrict__ out, const float* __restrict__ alpha, int n4)
{
    const float a = alpha[0];
    for (int i = blockIdx.x * blockDim.x + threadIdx.x; i < n4;
         i += gridDim.x * blockDim.x) {
        float4 v = reinterpret_cast<float4*>(out)[i];
        v.x = v.x >= 0.f ? v.x : a * v.x;
        v.y = v.y >= 0.f ? v.y : a * v.y;
        v.z = v.z >= 0.f ? v.z : a * v.z;
        v.w = v.w >= 0.f ? v.w : a * v.w;
        reinterpret_cast<float4*>(out)[i] = v;
    }
}

// ===========================================================================
extern "C" void kernel_launch(void* const* d_in, const int* in_sizes, int n_in,
                              void* d_out, int out_size, void* d_ws, size_t ws_size,
                              hipStream_t stream)
{
    const float* x     = (const float*)d_in[0];
    const float* W     = (const float*)d_in[1];
    const float* b     = (const float*)d_in[2];
    const float* alpha = (const float*)d_in[3];
    const int*   erow  = (const int*)d_in[4];
    const int*   ecol  = (const int*)d_in[5];
    const float* eval_ = (const float*)d_in[6];
    float* out = (float*)d_out;

    const int N = in_sizes[0] / IN_FT;   // 100000
    const int E = in_sizes[4];           // 1600000
    const int NB = (N + BROWS - 1) / BROWS;   // 782 buckets

    // ---- workspace: gcur (NB ints) | ebuf (NB*BCAP int2) | h fp16 ----
    auto al16 = [](size_t v) { return (v + 15) & ~15ull; };
    char* ws = (char*)d_ws;

    size_t off = 0;
    int*    gcur = (int*)(ws + off);  off += al16((size_t)NB * sizeof(int));
    int2*   ebuf = (int2*)(ws + off); off += al16((size_t)NB * BCAP * sizeof(int2));
    __half* h16  = (__half*)(ws + off); off += al16((size_t)N * OUT_FT * sizeof(__half));

    const bool fast_ok = (off <= ws_size) && (NB <= 1024) && (N <= (1 << 17));

    if (fast_ok) {
        hipMemsetAsync(gcur, 0, (size_t)NB * sizeof(int), stream);
        k_partition<<<PART_BLOCKS, 256, 0, stream>>>(
            erow, ecol, eval_, gcur, ebuf, E, NB);
        gcn_fc_fp16_kernel<<<(N + ROWS_PER_BLOCK - 1) / ROWS_PER_BLOCK, 256, 0, stream>>>(
            x, W, b, h16, N);
        k_bucket_gather<<<NB, 256, 0, stream>>>(h16, gcur, ebuf, alpha, out, N);
    } else {
        float* hf = (float*)ws;
        gcn_fc_kernel<<<(N + ROWS_PER_BLOCK - 1) / ROWS_PER_BLOCK, 256, 0, stream>>>(
            x, W, b, hf, N);
        hipMemsetAsync(d_out, 0, (size_t)N * OUT_FT * sizeof(float), stream);
        const long long st = (long long)E * 16;
        gcn_scatter_kernel<<<(st + 255) / 256, 256, 0, stream>>>(
            hf, erow, ecol, eval_, out, E);
        gcn_prelu_kernel<<<2048, 256, 0, stream>>>(out, alpha, (N * OUT_FT) / 4);
    }
}

// Round 7
// 265.462 us; speedup vs baseline: 3.1787x; 3.1787x over previous
//
#include <hip/hip_runtime.h>
#include <hip/hip_bf16.h>
#include <hip/hip_fp16.h>

#define IN_FT 128
#define OUT_FT 64
#define BROWS 128          // rows per bucket (low 7 bits of row)
#define BCAP  2560         // slots per bucket: mean 2046 + ~11 sigma
#define PART_BLOCKS 256    // blocks in partition kernel

// ===========================================================================
// FC (main path): h = x @ W + b, h stored FP16 (halves gather traffic).
// fp32 accumulate on vector ALU — no fp32 MFMA on CDNA4.
// ===========================================================================
constexpr int ROWS_PER_BLOCK = 64;
constexpr int XS_STRIDE = 132;

__global__ __launch_bounds__(256) void gcn_fc_fp16_kernel(
    const float* __restrict__ x, const float* __restrict__ W,
    const float* __restrict__ b, __half* __restrict__ h, int N)
{
    __shared__ float Wl[IN_FT * OUT_FT];
    __shared__ float xs[ROWS_PER_BLOCK * XS_STRIDE];

    const int tid  = threadIdx.x;
    const int row0 = blockIdx.x * ROWS_PER_BLOCK;

    for (int i = tid; i < (IN_FT * OUT_FT) / 4; i += 256)
        reinterpret_cast<float4*>(Wl)[i] = reinterpret_cast<const float4*>(W)[i];

    for (int i = tid; i < (ROWS_PER_BLOCK * IN_FT) / 4; i += 256) {
        const int r  = i / (IN_FT / 4);
        const int c4 = i % (IN_FT / 4);
        float4 v = make_float4(0.f, 0.f, 0.f, 0.f);
        if (row0 + r < N)
            v = reinterpret_cast<const float4*>(x + (size_t)(row0 + r) * IN_FT)[c4];
        reinterpret_cast<float4*>(&xs[r * XS_STRIDE])[c4] = v;
    }
    __syncthreads();

    const int jg = tid & 15;
    const int rg = tid >> 4;

    const float4 bv = reinterpret_cast<const float4*>(b)[jg];
    float acc[4][4];
#pragma unroll
    for (int rr = 0; rr < 4; ++rr) {
        acc[rr][0] = bv.x; acc[rr][1] = bv.y; acc[rr][2] = bv.z; acc[rr][3] = bv.w;
    }

    for (int k0 = 0; k0 < IN_FT; k0 += 4) {
        float wf[4][4];
#pragma unroll
        for (int kk = 0; kk < 4; ++kk) {
            const float4 t = *reinterpret_cast<const float4*>(&Wl[(k0 + kk) * OUT_FT + 4 * jg]);
            wf[kk][0] = t.x; wf[kk][1] = t.y; wf[kk][2] = t.z; wf[kk][3] = t.w;
        }
#pragma unroll
        for (int rr = 0; rr < 4; ++rr) {
            const float4 xv = *reinterpret_cast<const float4*>(&xs[(4 * rg + rr) * XS_STRIDE + k0]);
            const float xk[4] = {xv.x, xv.y, xv.z, xv.w};
#pragma unroll
            for (int kk = 0; kk < 4; ++kk)
#pragma unroll
                for (int jj = 0; jj < 4; ++jj)
                    acc[rr][jj] += xk[kk] * wf[kk][jj];
        }
    }

#pragma unroll
    for (int rr = 0; rr < 4; ++rr) {
        const int r = row0 + 4 * rg + rr;
        if (r < N) {
            __half2 p0 = __floats2half2_rn(acc[rr][0], acc[rr][1]);
            __half2 p1 = __floats2half2_rn(acc[rr][2], acc[rr][3]);
            uint2 pk;
            pk.x = *reinterpret_cast<unsigned*>(&p0);
            pk.y = *reinterpret_cast<unsigned*>(&p1);
            *reinterpret_cast<uint2*>(&h[(size_t)r * OUT_FT + 4 * jg]) = pk;
        }
    }
}

// ===========================================================================
// Partition (validated in R6): bucket edges by row>>7. Two-pass LDS histogram
// per block; ONE global returning atomic per (block,bin) to reserve spans.
// Writes packed {col | rowlow<<17, val} into bucket-major ebuf.
// ===========================================================================
__global__ __launch_bounds__(256) void k_partition(
    const int* __restrict__ erow, const int* __restrict__ ecol,
    const float* __restrict__ eval_, int* __restrict__ gcur,
    int2* __restrict__ ebuf, int E, int NB)
{
    __shared__ int hist[1024];
    __shared__ int base[1024];

    const int tid = threadIdx.x;
    const int CH  = (E + PART_BLOCKS - 1) / PART_BLOCKS;
    const int e0  = blockIdx.x * CH;
    const int e1  = min(E, e0 + CH);

    for (int i = tid; i < NB; i += 256) hist[i] = 0;
    __syncthreads();

    for (int i = e0 + tid; i < e1; i += 256)
        atomicAdd(&hist[erow[i] >> 7], 1);
    __syncthreads();

    for (int i = tid; i < NB; i += 256) {
        const int c = hist[i];
        base[i] = c ? atomicAdd(&gcur[i], c) : 0;
    }
    __syncthreads();
    for (int i = tid; i < NB; i += 256) hist[i] = 0;
    __syncthreads();

    for (int i = e0 + tid; i < e1; i += 256) {
        const int   r   = erow[i];
        const int   c   = ecol[i];
        const float v   = eval_[i];
        const int   bin = r >> 7;
        const int   lr  = atomicAdd(&hist[bin], 1);
        const int   slot = base[bin] + lr;
        if (slot < BCAP)   // statistically unreachable; memory-safety clamp
            ebuf[(size_t)bin * BCAP + slot] =
                make_int2(c | ((r & (BROWS - 1)) << 17), __float_as_int(v));
    }
}

// ===========================================================================
// Local CSR: one block per bucket. Stage bucket edges in LDS (<=20.5 KB),
// 128-counter LDS histogram + scan, write back row-sorted IN PLACE as
// {col, val}; emit srow[row] = {abs start, deg}. Zero per-edge global atomics.
// ===========================================================================
__global__ __launch_bounds__(256) void k_localcsr(
    const int* __restrict__ gcur, int2* __restrict__ ebuf,
    int2* __restrict__ srow, int N)
{
    __shared__ int2 stage[BCAP];     // 20.5 KB
    __shared__ int  hist[BROWS];
    __shared__ int  base[BROWS];
    __shared__ int  cur[BROWS];

    const int tid = threadIdx.x;
    const int bin = blockIdx.x;
    const int cnt = min(gcur[bin], BCAP);
    int2* bp = ebuf + (size_t)bin * BCAP;

    if (tid < BROWS) hist[tid] = 0;
    __syncthreads();

    // load to LDS + per-row count
    for (int i = tid; i < cnt; i += 256) {
        const int2 e = bp[i];
        stage[i] = e;
        atomicAdd(&hist[(e.x >> 17) & (BROWS - 1)], 1);
    }
    __syncthreads();

    // Hillis-Steele inclusive scan over 128 counters
    if (tid < BROWS) base[tid] = hist[tid];
    __syncthreads();
    for (int d = 1; d < BROWS; d <<= 1) {
        int v = 0;
        if (tid < BROWS && tid >= d) v = base[tid - d];
        __syncthreads();
        if (tid < BROWS) base[tid] += v;
        __syncthreads();
    }
    if (tid < BROWS) {
        const int ex = base[tid] - hist[tid];   // exclusive
        base[tid] = ex;
        cur[tid]  = ex;
        const int row = (bin << 7) + tid;
        if (row < N) srow[row] = make_int2(bin * BCAP + ex, hist[tid]);
    }
    __syncthreads();

    // scatter back row-sorted, strip row bits
    for (int i = tid; i < cnt; i += 256) {
        const int2 e = stage[i];
        const int  r = (e.x >> 17) & (BROWS - 1);
        const int  pos = atomicAdd(&cur[r], 1);
        bp[pos] = make_int2(e.x & 0x1FFFF, e.y);
    }
}

// ===========================================================================
// Gather (R5-proven shape): one wave per row, lane = feature, fp16 h,
// PReLU fused. 100K waves -> full latency hiding.
// ===========================================================================
__global__ __launch_bounds__(256) void k_gather(
    const __half* __restrict__ h, const int2* __restrict__ srow,
    const int2* __restrict__ ebuf, const float* __restrict__ alpha,
    float* __restrict__ out, int N)
{
    const int wid  = (int)((blockIdx.x * (size_t)blockDim.x + threadIdx.x) >> 6);
    const int lane = threadIdx.x & 63;
    if (wid >= N) return;

    const int2 sd   = srow[wid];
    const int start = sd.x;
    const int deg   = sd.y;

    float acc = 0.f;
    int j = 0;
    for (; j + 4 <= deg; j += 4) {
        const int2 cv0 = ebuf[start + j + 0];
        const int2 cv1 = ebuf[start + j + 1];
        const int2 cv2 = ebuf[start + j + 2];
        const int2 cv3 = ebuf[start + j + 3];
        const float h0 = __half2float(h[(size_t)cv0.x * OUT_FT + lane]);
        const float h1 = __half2float(h[(size_t)cv1.x * OUT_FT + lane]);
        const float h2 = __half2float(h[(size_t)cv2.x * OUT_FT + lane]);
        const float h3 = __half2float(h[(size_t)cv3.x * OUT_FT + lane]);
        acc += __int_as_float(cv0.y) * h0;
        acc += __int_as_float(cv1.y) * h1;
        acc += __int_as_float(cv2.y) * h2;
        acc += __int_as_float(cv3.y) * h3;
    }
    for (; j < deg; ++j) {
        const int2 cv = ebuf[start + j];
        acc += __int_as_float(cv.y) * __half2float(h[(size_t)cv.x * OUT_FT + lane]);
    }

    const float a = alpha[0];
    out[(size_t)wid * OUT_FT + lane] = (acc >= 0.f) ? acc : a * acc;
}

// ===========================================================================
// Fallback path (ws too small / N too large for 17-bit col pack)
// ===========================================================================
__global__ __launch_bounds__(256) void gcn_fc_kernel(
    const float* __restrict__ x, const float* __restrict__ W,
    const float* __restrict__ b, float* __restrict__ h, int N)
{
    __shared__ float Wl[IN_FT * OUT_FT];
    __shared__ float xs[ROWS_PER_BLOCK * XS_STRIDE];

    const int tid  = threadIdx.x;
    const int row0 = blockIdx.x * ROWS_PER_BLOCK;

    for (int i = tid; i < (IN_FT * OUT_FT) / 4; i += 256)
        reinterpret_cast<float4*>(Wl)[i] = reinterpret_cast<const float4*>(W)[i];

    for (int i = tid; i < (ROWS_PER_BLOCK * IN_FT) / 4; i += 256) {
        const int r  = i / (IN_FT / 4);
        const int c4 = i % (IN_FT / 4);
        float4 v = make_float4(0.f, 0.f, 0.f, 0.f);
        if (row0 + r < N)
            v = reinterpret_cast<const float4*>(x + (size_t)(row0 + r) * IN_FT)[c4];
        reinterpret_cast<float4*>(&xs[r * XS_STRIDE])[c4] = v;
    }
    __syncthreads();

    const int jg = tid & 15;
    const int rg = tid >> 4;

    const float4 bv = reinterpret_cast<const float4*>(b)[jg];
    float acc[4][4];
#pragma unroll
    for (int rr = 0; rr < 4; ++rr) {
        acc[rr][0] = bv.x; acc[rr][1] = bv.y; acc[rr][2] = bv.z; acc[rr][3] = bv.w;
    }

    for (int k0 = 0; k0 < IN_FT; k0 += 4) {
        float wf[4][4];
#pragma unroll
        for (int kk = 0; kk < 4; ++kk) {
            const float4 t = *reinterpret_cast<const float4*>(&Wl[(k0 + kk) * OUT_FT + 4 * jg]);
            wf[kk][0] = t.x; wf[kk][1] = t.y; wf[kk][2] = t.z; wf[kk][3] = t.w;
        }
#pragma unroll
        for (int rr = 0; rr < 4; ++rr) {
            const float4 xv = *reinterpret_cast<const float4*>(&xs[(4 * rg + rr) * XS_STRIDE + k0]);
            const float xk[4] = {xv.x, xv.y, xv.z, xv.w};
#pragma unroll
            for (int kk = 0; kk < 4; ++kk)
#pragma unroll
                for (int jj = 0; jj < 4; ++jj)
                    acc[rr][jj] += xk[kk] * wf[kk][jj];
        }
    }

#pragma unroll
    for (int rr = 0; rr < 4; ++rr) {
        const int r = row0 + 4 * rg + rr;
        if (r < N)
            *reinterpret_cast<float4*>(&h[(size_t)r * OUT_FT + 4 * jg]) =
                make_float4(acc[rr][0], acc[rr][1], acc[rr][2], acc[rr][3]);
    }
}

__global__ __launch_bounds__(256) void gcn_scatter_kernel(
    const float* __restrict__ h, const int* __restrict__ erow,
    const int* __restrict__ ecol, const float* __restrict__ eval_,
    float* __restrict__ out, int E)
{
    const int t  = blockIdx.x * blockDim.x + threadIdx.x;
    const int e  = t >> 4;
    const int fg = (t & 15) * 4;
    if (e >= E) return;
    const int   col = ecol[e];
    const int   row = erow[e];
    const float v   = eval_[e];
    const float4 hv = *reinterpret_cast<const float4*>(&h[(size_t)col * OUT_FT + fg]);
    float* op = &out[(size_t)row * OUT_FT + fg];
    atomicAdd(op + 0, v * hv.x);
    atomicAdd(op + 1, v * hv.y);
    atomicAdd(op + 2, v * hv.z);
    atomicAdd(op + 3, v * hv.w);
}

__global__ __launch_bounds__(256) void gcn_prelu_kernel(
    float* __restrict__ out, const float* __restrict__ alpha, int n4)
{
    const float a = alpha[0];
    for (int i = blockIdx.x * blockDim.x + threadIdx.x; i < n4;
         i += gridDim.x * blockDim.x) {
        float4 v = reinterpret_cast<float4*>(out)[i];
        v.x = v.x >= 0.f ? v.x : a * v.x;
        v.y = v.y >= 0.f ? v.y : a * v.y;
        v.z = v.z >= 0.f ? v.z : a * v.z;
        v.w = v.w >= 0.f ? v.w : a * v.w;
        reinterpret_cast<float4*>(out)[i] = v;
    }
}

// ===========================================================================
extern "C" void kernel_launch(void* const* d_in, const int* in_sizes, int n_in,
                              void* d_out, int out_size, void* d_ws, size_t ws_size,
                              hipStream_t stream)
{
    const float* x     = (const float*)d_in[0];
    const float* W     = (const float*)d_in[1];
    const float* b     = (const float*)d_in[2];
    const float* alpha = (const float*)d_in[3];
    const int*   erow  = (const int*)d_in[4];
    const int*   ecol  = (const int*)d_in[5];
    const float* eval_ = (const float*)d_in[6];
    float* out = (float*)d_out;

    const int N = in_sizes[0] / IN_FT;   // 100000
    const int E = in_sizes[4];           // 1600000
    const int NB = (N + BROWS - 1) / BROWS;   // 782 buckets

    // ---- workspace: gcur | ebuf | srow | h fp16  (~29.6 MB) ----
    auto al16 = [](size_t v) { return (v + 15) & ~15ull; };
    char* ws = (char*)d_ws;

    size_t off = 0;
    int*    gcur = (int*)(ws + off);   off += al16((size_t)NB * sizeof(int));
    int2*   ebuf = (int2*)(ws + off);  off += al16((size_t)NB * BCAP * sizeof(int2));
    int2*   srow = (int2*)(ws + off);  off += al16((size_t)N * sizeof(int2));
    __half* h16  = (__half*)(ws + off); off += al16((size_t)N * OUT_FT * sizeof(__half));

    const bool fast_ok = (off <= ws_size) && (NB <= 1024) && (N <= (1 << 17));

    if (fast_ok) {
        hipMemsetAsync(gcur, 0, (size_t)NB * sizeof(int), stream);
        k_partition<<<PART_BLOCKS, 256, 0, stream>>>(
            erow, ecol, eval_, gcur, ebuf, E, NB);
        k_localcsr<<<NB, 256, 0, stream>>>(gcur, ebuf, srow, N);
        gcn_fc_fp16_kernel<<<(N + ROWS_PER_BLOCK - 1) / ROWS_PER_BLOCK, 256, 0, stream>>>(
            x, W, b, h16, N);
        const size_t gthreads = (size_t)N * 64;
        k_gather<<<(int)((gthreads + 255) / 256), 256, 0, stream>>>(
            h16, srow, ebuf, alpha, out, N);
    } else {
        float* hf = (float*)ws;
        gcn_fc_kernel<<<(N + ROWS_PER_BLOCK - 1) / ROWS_PER_BLOCK, 256, 0, stream>>>(
            x, W, b, hf, N);
        hipMemsetAsync(d_out, 0, (size_t)N * OUT_FT * sizeof(float), stream);
        const long long st = (long long)E * 16;
        gcn_scatter_kernel<<<(st + 255) / 256, 256, 0, stream>>>(
            hf, erow, ecol, eval_, out, E);
        gcn_prelu_kernel<<<2048, 256, 0, stream>>>(out, alpha, (N * OUT_FT) / 4);
    }
}

// Round 8
// 237.708 us; speedup vs baseline: 3.5499x; 1.1168x over previous
//
#include <hip/hip_runtime.h>
#include <hip/hip_bf16.h>
#include <hip/hip_fp16.h>

#define IN_FT 128
#define OUT_FT 64
#define BROWS 128          // rows per bucket (low 7 bits of row)
#define BCAP  2560         // slots per bucket: mean 2046 + ~11 sigma
#define PART_BLOCKS 256    // blocks in partition kernel

// ===========================================================================
// FC (main path): h = x @ W + b, h stored FP16 (halves gather traffic).
// fp32 accumulate on vector ALU — no fp32 MFMA on CDNA4.
// ===========================================================================
constexpr int ROWS_PER_BLOCK = 64;
constexpr int XS_STRIDE = 132;

__global__ __launch_bounds__(256) void gcn_fc_fp16_kernel(
    const float* __restrict__ x, const float* __restrict__ W,
    const float* __restrict__ b, __half* __restrict__ h, int N)
{
    __shared__ float Wl[IN_FT * OUT_FT];
    __shared__ float xs[ROWS_PER_BLOCK * XS_STRIDE];

    const int tid  = threadIdx.x;
    const int row0 = blockIdx.x * ROWS_PER_BLOCK;

    for (int i = tid; i < (IN_FT * OUT_FT) / 4; i += 256)
        reinterpret_cast<float4*>(Wl)[i] = reinterpret_cast<const float4*>(W)[i];

    for (int i = tid; i < (ROWS_PER_BLOCK * IN_FT) / 4; i += 256) {
        const int r  = i / (IN_FT / 4);
        const int c4 = i % (IN_FT / 4);
        float4 v = make_float4(0.f, 0.f, 0.f, 0.f);
        if (row0 + r < N)
            v = reinterpret_cast<const float4*>(x + (size_t)(row0 + r) * IN_FT)[c4];
        reinterpret_cast<float4*>(&xs[r * XS_STRIDE])[c4] = v;
    }
    __syncthreads();

    const int jg = tid & 15;
    const int rg = tid >> 4;

    const float4 bv = reinterpret_cast<const float4*>(b)[jg];
    float acc[4][4];
#pragma unroll
    for (int rr = 0; rr < 4; ++rr) {
        acc[rr][0] = bv.x; acc[rr][1] = bv.y; acc[rr][2] = bv.z; acc[rr][3] = bv.w;
    }

    for (int k0 = 0; k0 < IN_FT; k0 += 4) {
        float wf[4][4];
#pragma unroll
        for (int kk = 0; kk < 4; ++kk) {
            const float4 t = *reinterpret_cast<const float4*>(&Wl[(k0 + kk) * OUT_FT + 4 * jg]);
            wf[kk][0] = t.x; wf[kk][1] = t.y; wf[kk][2] = t.z; wf[kk][3] = t.w;
        }
#pragma unroll
        for (int rr = 0; rr < 4; ++rr) {
            const float4 xv = *reinterpret_cast<const float4*>(&xs[(4 * rg + rr) * XS_STRIDE + k0]);
            const float xk[4] = {xv.x, xv.y, xv.z, xv.w};
#pragma unroll
            for (int kk = 0; kk < 4; ++kk)
#pragma unroll
                for (int jj = 0; jj < 4; ++jj)
                    acc[rr][jj] += xk[kk] * wf[kk][jj];
        }
    }

#pragma unroll
    for (int rr = 0; rr < 4; ++rr) {
        const int r = row0 + 4 * rg + rr;
        if (r < N) {
            __half2 p0 = __floats2half2_rn(acc[rr][0], acc[rr][1]);
            __half2 p1 = __floats2half2_rn(acc[rr][2], acc[rr][3]);
            uint2 pk;
            pk.x = *reinterpret_cast<unsigned*>(&p0);
            pk.y = *reinterpret_cast<unsigned*>(&p1);
            *reinterpret_cast<uint2*>(&h[(size_t)r * OUT_FT + 4 * jg]) = pk;
        }
    }
}

// ===========================================================================
// Partition: bucket edges by row>>7. Two-pass LDS histogram per block;
// ONE global returning atomic per (block,bin). 4 edges/thread vectorized.
// Writes packed {col | rowlow<<17, val} into bucket-major ebuf.
// ===========================================================================
__global__ __launch_bounds__(256) void k_partition(
    const int* __restrict__ erow, const int* __restrict__ ecol,
    const float* __restrict__ eval_, int* __restrict__ gcur,
    int2* __restrict__ ebuf, int E, int NB)
{
    __shared__ int hist[1024];
    __shared__ int base[1024];

    const int tid = threadIdx.x;
    // 1024-aligned chunks so int4 loads stay 16B-aligned
    const int CH  = (((E + PART_BLOCKS - 1) / PART_BLOCKS) + 1023) & ~1023;
    const int e0  = blockIdx.x * CH;
    const int e1  = min(E, e0 + CH);

    for (int i = tid; i < NB; i += 256) hist[i] = 0;
    __syncthreads();

    // pass A: per-block histogram, 4 edges/thread
    for (int i = e0 + tid * 4; i < e1; i += 1024) {
        if (i + 3 < e1) {
            const int4 r4 = *reinterpret_cast<const int4*>(&erow[i]);
            atomicAdd(&hist[r4.x >> 7], 1);
            atomicAdd(&hist[r4.y >> 7], 1);
            atomicAdd(&hist[r4.z >> 7], 1);
            atomicAdd(&hist[r4.w >> 7], 1);
        } else {
            for (int k = i; k < e1; ++k) atomicAdd(&hist[erow[k] >> 7], 1);
        }
    }
    __syncthreads();

    // reserve spans: one global returning atomic per nonzero bin
    for (int i = tid; i < NB; i += 256) {
        const int c = hist[i];
        base[i] = c ? atomicAdd(&gcur[i], c) : 0;
    }
    __syncthreads();
    for (int i = tid; i < NB; i += 256) hist[i] = 0;
    __syncthreads();

    // pass B: LDS rank + scattered 8B write, 4 edges/thread
    for (int i = e0 + tid * 4; i < e1; i += 1024) {
        if (i + 3 < e1) {
            const int4   r4 = *reinterpret_cast<const int4*>(&erow[i]);
            const int4   c4 = *reinterpret_cast<const int4*>(&ecol[i]);
            const float4 v4 = *reinterpret_cast<const float4*>(&eval_[i]);
            const int rr[4] = {r4.x, r4.y, r4.z, r4.w};
            const int cc[4] = {c4.x, c4.y, c4.z, c4.w};
            const float vv[4] = {v4.x, v4.y, v4.z, v4.w};
#pragma unroll
            for (int u = 0; u < 4; ++u) {
                const int bin  = rr[u] >> 7;
                const int lr   = atomicAdd(&hist[bin], 1);
                const int slot = base[bin] + lr;
                if (slot < BCAP)
                    ebuf[(size_t)bin * BCAP + slot] =
                        make_int2(cc[u] | ((rr[u] & (BROWS - 1)) << 17),
                                  __float_as_int(vv[u]));
            }
        } else {
            for (int k = i; k < e1; ++k) {
                const int bin  = erow[k] >> 7;
                const int lr   = atomicAdd(&hist[bin], 1);
                const int slot = base[bin] + lr;
                if (slot < BCAP)
                    ebuf[(size_t)bin * BCAP + slot] =
                        make_int2(ecol[k] | ((erow[k] & (BROWS - 1)) << 17),
                                  __float_as_int(eval_[k]));
            }
        }
    }
}

// ===========================================================================
// Local CSR: one block per bucket. Stage edges in LDS (int4 = 2 edges/load),
// 128-counter histogram + scan, write back row-sorted IN PLACE as {col,val};
// emit srow[row] = {abs start, deg}. Zero per-edge global atomics.
// ===========================================================================
__global__ __launch_bounds__(256) void k_localcsr(
    const int* __restrict__ gcur, int2* __restrict__ ebuf,
    int2* __restrict__ srow, int N)
{
    __shared__ int2 stage[BCAP];     // 20.5 KB
    __shared__ int  hist[BROWS];
    __shared__ int  base[BROWS];
    __shared__ int  cur[BROWS];

    const int tid = threadIdx.x;
    const int bin = blockIdx.x;
    const int cnt = min(gcur[bin], BCAP);
    int2* bp = ebuf + (size_t)bin * BCAP;

    if (tid < BROWS) hist[tid] = 0;
    __syncthreads();

    // load to LDS (2 edges per 16B load; bp is 16B-aligned) + per-row count
    for (int i = tid * 2; i < cnt; i += 512) {
        if (i + 1 < cnt) {
            const int4 p = *reinterpret_cast<const int4*>(&bp[i]);
            stage[i]     = make_int2(p.x, p.y);
            stage[i + 1] = make_int2(p.z, p.w);
            atomicAdd(&hist[(p.x >> 17) & (BROWS - 1)], 1);
            atomicAdd(&hist[(p.z >> 17) & (BROWS - 1)], 1);
        } else {
            const int2 e = bp[i];
            stage[i] = e;
            atomicAdd(&hist[(e.x >> 17) & (BROWS - 1)], 1);
        }
    }
    __syncthreads();

    // Hillis-Steele inclusive scan over 128 counters
    if (tid < BROWS) base[tid] = hist[tid];
    __syncthreads();
    for (int d = 1; d < BROWS; d <<= 1) {
        int v = 0;
        if (tid < BROWS && tid >= d) v = base[tid - d];
        __syncthreads();
        if (tid < BROWS) base[tid] += v;
        __syncthreads();
    }
    if (tid < BROWS) {
        const int ex = base[tid] - hist[tid];   // exclusive
        cur[tid] = ex;
        const int row = (bin << 7) + tid;
        if (row < N) srow[row] = make_int2(bin * BCAP + ex, hist[tid]);
    }
    __syncthreads();

    // scatter back row-sorted, strip row bits
    for (int i = tid; i < cnt; i += 256) {
        const int2 e = stage[i];
        const int  r = (e.x >> 17) & (BROWS - 1);
        const int  pos = atomicAdd(&cur[r], 1);
        bp[pos] = make_int2(e.x & 0x1FFFF, e.y);
    }
}

// ===========================================================================
// Gather: one wave per row, lane = feature, fp16 h, PReLU fused.
// 8-deep unroll: 8 independent h-gathers in flight per wave (was 4).
// ===========================================================================
__global__ __launch_bounds__(256) void k_gather(
    const __half* __restrict__ h, const int2* __restrict__ srow,
    const int2* __restrict__ ebuf, const float* __restrict__ alpha,
    float* __restrict__ out, int N)
{
    const int wid  = (int)((blockIdx.x * (size_t)blockDim.x + threadIdx.x) >> 6);
    const int lane = threadIdx.x & 63;
    if (wid >= N) return;

    const int2 sd   = srow[wid];
    const int start = sd.x;
    const int deg   = sd.y;

    float acc = 0.f;
    int j = 0;
    for (; j + 8 <= deg; j += 8) {
        int2 cv[8];
#pragma unroll
        for (int u = 0; u < 8; ++u) cv[u] = ebuf[start + j + u];
        float hv[8];
#pragma unroll
        for (int u = 0; u < 8; ++u)
            hv[u] = __half2float(h[(size_t)cv[u].x * OUT_FT + lane]);
#pragma unroll
        for (int u = 0; u < 8; ++u)
            acc += __int_as_float(cv[u].y) * hv[u];
    }
    if (j + 4 <= deg) {
        int2 cv[4];
#pragma unroll
        for (int u = 0; u < 4; ++u) cv[u] = ebuf[start + j + u];
        float hv[4];
#pragma unroll
        for (int u = 0; u < 4; ++u)
            hv[u] = __half2float(h[(size_t)cv[u].x * OUT_FT + lane]);
#pragma unroll
        for (int u = 0; u < 4; ++u)
            acc += __int_as_float(cv[u].y) * hv[u];
        j += 4;
    }
    for (; j < deg; ++j) {
        const int2 cv = ebuf[start + j];
        acc += __int_as_float(cv.y) * __half2float(h[(size_t)cv.x * OUT_FT + lane]);
    }

    const float a = alpha[0];
    out[(size_t)wid * OUT_FT + lane] = (acc >= 0.f) ? acc : a * acc;
}

// ===========================================================================
// Fallback path (ws too small / N too large for 17-bit col pack)
// ===========================================================================
__global__ __launch_bounds__(256) void gcn_fc_kernel(
    const float* __restrict__ x, const float* __restrict__ W,
    const float* __restrict__ b, float* __restrict__ h, int N)
{
    __shared__ float Wl[IN_FT * OUT_FT];
    __shared__ float xs[ROWS_PER_BLOCK * XS_STRIDE];

    const int tid  = threadIdx.x;
    const int row0 = blockIdx.x * ROWS_PER_BLOCK;

    for (int i = tid; i < (IN_FT * OUT_FT) / 4; i += 256)
        reinterpret_cast<float4*>(Wl)[i] = reinterpret_cast<const float4*>(W)[i];

    for (int i = tid; i < (ROWS_PER_BLOCK * IN_FT) / 4; i += 256) {
        const int r  = i / (IN_FT / 4);
        const int c4 = i % (IN_FT / 4);
        float4 v = make_float4(0.f, 0.f, 0.f, 0.f);
        if (row0 + r < N)
            v = reinterpret_cast<const float4*>(x + (size_t)(row0 + r) * IN_FT)[c4];
        reinterpret_cast<float4*>(&xs[r * XS_STRIDE])[c4] = v;
    }
    __syncthreads();

    const int jg = tid & 15;
    const int rg = tid >> 4;

    const float4 bv = reinterpret_cast<const float4*>(b)[jg];
    float acc[4][4];
#pragma unroll
    for (int rr = 0; rr < 4; ++rr) {
        acc[rr][0] = bv.x; acc[rr][1] = bv.y; acc[rr][2] = bv.z; acc[rr][3] = bv.w;
    }

    for (int k0 = 0; k0 < IN_FT; k0 += 4) {
        float wf[4][4];
#pragma unroll
        for (int kk = 0; kk < 4; ++kk) {
            const float4 t = *reinterpret_cast<const float4*>(&Wl[(k0 + kk) * OUT_FT + 4 * jg]);
            wf[kk][0] = t.x; wf[kk][1] = t.y; wf[kk][2] = t.z; wf[kk][3] = t.w;
        }
#pragma unroll
        for (int rr = 0; rr < 4; ++rr) {
            const float4 xv = *reinterpret_cast<const float4*>(&xs[(4 * rg + rr) * XS_STRIDE + k0]);
            const float xk[4] = {xv.x, xv.y, xv.z, xv.w};
#pragma unroll
            for (int kk = 0; kk < 4; ++kk)
#pragma unroll
                for (int jj = 0; jj < 4; ++jj)
                    acc[rr][jj] += xk[kk] * wf[kk][jj];
        }
    }

#pragma unroll
    for (int rr = 0; rr < 4; ++rr) {
        const int r = row0 + 4 * rg + rr;
        if (r < N)
            *reinterpret_cast<float4*>(&h[(size_t)r * OUT_FT + 4 * jg]) =
                make_float4(acc[rr][0], acc[rr][1], acc[rr][2], acc[rr][3]);
    }
}

__global__ __launch_bounds__(256) void gcn_scatter_kernel(
    const float* __restrict__ h, const int* __restrict__ erow,
    const int* __restrict__ ecol, const float* __restrict__ eval_,
    float* __restrict__ out, int E)
{
    const int t  = blockIdx.x * blockDim.x + threadIdx.x;
    const int e  = t >> 4;
    const int fg = (t & 15) * 4;
    if (e >= E) return;
    const int   col = ecol[e];
    const int   row = erow[e];
    const float v   = eval_[e];
    const float4 hv = *reinterpret_cast<const float4*>(&h[(size_t)col * OUT_FT + fg]);
    float* op = &out[(size_t)row * OUT_FT + fg];
    atomicAdd(op + 0, v * hv.x);
    atomicAdd(op + 1, v * hv.y);
    atomicAdd(op + 2, v * hv.z);
    atomicAdd(op + 3, v * hv.w);
}

__global__ __launch_bounds__(256) void gcn_prelu_kernel(
    float* __restrict__ out, const float* __restrict__ alpha, int n4)
{
    const float a = alpha[0];
    for (int i = blockIdx.x * blockDim.x + threadIdx.x; i < n4;
         i += gridDim.x * blockDim.x) {
        float4 v = reinterpret_cast<float4*>(out)[i];
        v.x = v.x >= 0.f ? v.x : a * v.x;
        v.y = v.y >= 0.f ? v.y : a * v.y;
        v.z = v.z >= 0.f ? v.z : a * v.z;
        v.w = v.w >= 0.f ? v.w : a * v.w;
        reinterpret_cast<float4*>(out)[i] = v;
    }
}

// ===========================================================================
extern "C" void kernel_launch(void* const* d_in, const int* in_sizes, int n_in,
                              void* d_out, int out_size, void* d_ws, size_t ws_size,
                              hipStream_t stream)
{
    const float* x     = (const float*)d_in[0];
    const float* W     = (const float*)d_in[1];
    const float* b     = (const float*)d_in[2];
    const float* alpha = (const float*)d_in[3];
    const int*   erow  = (const int*)d_in[4];
    const int*   ecol  = (const int*)d_in[5];
    const float* eval_ = (const float*)d_in[6];
    float* out = (float*)d_out;

    const int N = in_sizes[0] / IN_FT;   // 100000
    const int E = in_sizes[4];           // 1600000
    const int NB = (N + BROWS - 1) / BROWS;   // 782 buckets

    // ---- workspace: gcur | ebuf | srow | h fp16  (~30 MB) ----
    auto al16 = [](size_t v) { return (v + 15) & ~15ull; };
    char* ws = (char*)d_ws;

    size_t off = 0;
    int*    gcur = (int*)(ws + off);   off += al16((size_t)NB * sizeof(int));
    int2*   ebuf = (int2*)(ws + off);  off += al16((size_t)NB * BCAP * sizeof(int2));
    int2*   srow = (int2*)(ws + off);  off += al16((size_t)N * sizeof(int2));
    __half* h16  = (__half*)(ws + off); off += al16((size_t)N * OUT_FT * sizeof(__half));

    const bool fast_ok = (off <= ws_size) && (NB <= 1024) && (N <= (1 << 17));

    if (fast_ok) {
        hipMemsetAsync(gcur, 0, (size_t)NB * sizeof(int), stream);
        k_partition<<<PART_BLOCKS, 256, 0, stream>>>(
            erow, ecol, eval_, gcur, ebuf, E, NB);
        k_localcsr<<<NB, 256, 0, stream>>>(gcur, ebuf, srow, N);
        gcn_fc_fp16_kernel<<<(N + ROWS_PER_BLOCK - 1) / ROWS_PER_BLOCK, 256, 0, stream>>>(
            x, W, b, h16, N);
        const size_t gthreads = (size_t)N * 64;
        k_gather<<<(int)((gthreads + 255) / 256), 256, 0, stream>>>(
            h16, srow, ebuf, alpha, out, N);
    } else {
        float* hf = (float*)ws;
        gcn_fc_kernel<<<(N + ROWS_PER_BLOCK - 1) / ROWS_PER_BLOCK, 256, 0, stream>>>(
            x, W, b, hf, N);
        hipMemsetAsync(d_out, 0, (size_t)N * OUT_FT * sizeof(float), stream);
        const long long st = (long long)E * 16;
        gcn_scatter_kernel<<<(st + 255) / 256, 256, 0, stream>>>(
            hf, erow, ecol, eval_, out, E);
        gcn_prelu_kernel<<<2048, 256, 0, stream>>>(out, alpha, (N * OUT_FT) / 4);
    }
}

// Round 10
// 229.266 us; speedup vs baseline: 3.6806x; 1.0368x over previous
//
#include <hip/hip_runtime.h>
#include <hip/hip_bf16.h>
#include <hip/hip_fp16.h>

#define IN_FT 128
#define OUT_FT 64
#define BROWS 128          // rows per bucket (low 7 bits of row)
#define BCAP  2560         // slots per bucket: mean 2046 + ~11 sigma
#define PART_BLOCKS 256    // blocks in partition kernel

// ===========================================================================
// FC (main path): h = x @ W + b, h stored FP16 (halves gather traffic).
// fp32 accumulate on vector ALU — no fp32 MFMA on CDNA4.
// ===========================================================================
constexpr int ROWS_PER_BLOCK = 64;
constexpr int XS_STRIDE = 132;

__global__ __launch_bounds__(256) void gcn_fc_fp16_kernel(
    const float* __restrict__ x, const float* __restrict__ W,
    const float* __restrict__ b, __half* __restrict__ h, int N)
{
    __shared__ float Wl[IN_FT * OUT_FT];
    __shared__ float xs[ROWS_PER_BLOCK * XS_STRIDE];

    const int tid  = threadIdx.x;
    const int row0 = blockIdx.x * ROWS_PER_BLOCK;

    for (int i = tid; i < (IN_FT * OUT_FT) / 4; i += 256)
        reinterpret_cast<float4*>(Wl)[i] = reinterpret_cast<const float4*>(W)[i];

    for (int i = tid; i < (ROWS_PER_BLOCK * IN_FT) / 4; i += 256) {
        const int r  = i / (IN_FT / 4);
        const int c4 = i % (IN_FT / 4);
        float4 v = make_float4(0.f, 0.f, 0.f, 0.f);
        if (row0 + r < N)
            v = reinterpret_cast<const float4*>(x + (size_t)(row0 + r) * IN_FT)[c4];
        reinterpret_cast<float4*>(&xs[r * XS_STRIDE])[c4] = v;
    }
    __syncthreads();

    const int jg = tid & 15;
    const int rg = tid >> 4;

    const float4 bv = reinterpret_cast<const float4*>(b)[jg];
    float acc[4][4];
#pragma unroll
    for (int rr = 0; rr < 4; ++rr) {
        acc[rr][0] = bv.x; acc[rr][1] = bv.y; acc[rr][2] = bv.z; acc[rr][3] = bv.w;
    }

    for (int k0 = 0; k0 < IN_FT; k0 += 4) {
        float wf[4][4];
#pragma unroll
        for (int kk = 0; kk < 4; ++kk) {
            const float4 t = *reinterpret_cast<const float4*>(&Wl[(k0 + kk) * OUT_FT + 4 * jg]);
            wf[kk][0] = t.x; wf[kk][1] = t.y; wf[kk][2] = t.z; wf[kk][3] = t.w;
        }
#pragma unroll
        for (int rr = 0; rr < 4; ++rr) {
            const float4 xv = *reinterpret_cast<const float4*>(&xs[(4 * rg + rr) * XS_STRIDE + k0]);
            const float xk[4] = {xv.x, xv.y, xv.z, xv.w};
#pragma unroll
            for (int kk = 0; kk < 4; ++kk)
#pragma unroll
                for (int jj = 0; jj < 4; ++jj)
                    acc[rr][jj] += xk[kk] * wf[kk][jj];
        }
    }

#pragma unroll
    for (int rr = 0; rr < 4; ++rr) {
        const int r = row0 + 4 * rg + rr;
        if (r < N) {
            __half2 p0 = __floats2half2_rn(acc[rr][0], acc[rr][1]);
            __half2 p1 = __floats2half2_rn(acc[rr][2], acc[rr][3]);
            uint2 pk;
            pk.x = *reinterpret_cast<unsigned*>(&p0);
            pk.y = *reinterpret_cast<unsigned*>(&p1);
            *reinterpret_cast<uint2*>(&h[(size_t)r * OUT_FT + 4 * jg]) = pk;
        }
    }
}

// ===========================================================================
// Partition: bucket edges by row>>7. Two-pass LDS histogram per block;
// ONE global returning atomic per (block,bin). 4 edges/thread vectorized.
// Writes packed {col | rowlow<<17, val} into bucket-major ebuf.
// ===========================================================================
__global__ __launch_bounds__(256) void k_partition(
    const int* __restrict__ erow, const int* __restrict__ ecol,
    const float* __restrict__ eval_, int* __restrict__ gcur,
    int2* __restrict__ ebuf, int E, int NB)
{
    __shared__ int hist[1024];
    __shared__ int base[1024];

    const int tid = threadIdx.x;
    // 1024-aligned chunks so int4 loads stay 16B-aligned
    const int CH  = (((E + PART_BLOCKS - 1) / PART_BLOCKS) + 1023) & ~1023;
    const int e0  = blockIdx.x * CH;
    const int e1  = min(E, e0 + CH);

    for (int i = tid; i < NB; i += 256) hist[i] = 0;
    __syncthreads();

    // pass A: per-block histogram, 4 edges/thread
    for (int i = e0 + tid * 4; i < e1; i += 1024) {
        if (i + 3 < e1) {
            const int4 r4 = *reinterpret_cast<const int4*>(&erow[i]);
            atomicAdd(&hist[r4.x >> 7], 1);
            atomicAdd(&hist[r4.y >> 7], 1);
            atomicAdd(&hist[r4.z >> 7], 1);
            atomicAdd(&hist[r4.w >> 7], 1);
        } else {
            for (int k = i; k < e1; ++k) atomicAdd(&hist[erow[k] >> 7], 1);
        }
    }
    __syncthreads();

    // reserve spans: one global returning atomic per nonzero bin
    for (int i = tid; i < NB; i += 256) {
        const int c = hist[i];
        base[i] = c ? atomicAdd(&gcur[i], c) : 0;
    }
    __syncthreads();
    for (int i = tid; i < NB; i += 256) hist[i] = 0;
    __syncthreads();

    // pass B: LDS rank + scattered 8B write, 4 edges/thread
    for (int i = e0 + tid * 4; i < e1; i += 1024) {
        if (i + 3 < e1) {
            const int4   r4 = *reinterpret_cast<const int4*>(&erow[i]);
            const int4   c4 = *reinterpret_cast<const int4*>(&ecol[i]);
            const float4 v4 = *reinterpret_cast<const float4*>(&eval_[i]);
            const int rr[4] = {r4.x, r4.y, r4.z, r4.w};
            const int cc[4] = {c4.x, c4.y, c4.z, c4.w};
            const float vv[4] = {v4.x, v4.y, v4.z, v4.w};
#pragma unroll
            for (int u = 0; u < 4; ++u) {
                const int bin  = rr[u] >> 7;
                const int lr   = atomicAdd(&hist[bin], 1);
                const int slot = base[bin] + lr;
                if (slot < BCAP)
                    ebuf[(size_t)bin * BCAP + slot] =
                        make_int2(cc[u] | ((rr[u] & (BROWS - 1)) << 17),
                                  __float_as_int(vv[u]));
            }
        } else {
            for (int k = i; k < e1; ++k) {
                const int bin  = erow[k] >> 7;
                const int lr   = atomicAdd(&hist[bin], 1);
                const int slot = base[bin] + lr;
                if (slot < BCAP)
                    ebuf[(size_t)bin * BCAP + slot] =
                        make_int2(ecol[k] | ((erow[k] & (BROWS - 1)) << 17),
                                  __float_as_int(eval_[k]));
            }
        }
    }
}

// ===========================================================================
// Local CSR: one block per bucket. Stage edges in LDS (int4 = 2 edges/load),
// 128-counter histogram + scan, write back row-sorted IN PLACE as {col,val};
// emit srow[row] = {abs start, deg}. Zero per-edge global atomics.
// ===========================================================================
__global__ __launch_bounds__(256) void k_localcsr(
    const int* __restrict__ gcur, int2* __restrict__ ebuf,
    int2* __restrict__ srow, int N)
{
    __shared__ int2 stage[BCAP];     // 20.5 KB
    __shared__ int  hist[BROWS];
    __shared__ int  base[BROWS];
    __shared__ int  cur[BROWS];

    const int tid = threadIdx.x;
    const int bin = blockIdx.x;
    const int cnt = min(gcur[bin], BCAP);
    int2* bp = ebuf + (size_t)bin * BCAP;

    if (tid < BROWS) hist[tid] = 0;
    __syncthreads();

    // load to LDS (2 edges per 16B load; bp is 16B-aligned) + per-row count
    for (int i = tid * 2; i < cnt; i += 512) {
        if (i + 1 < cnt) {
            const int4 p = *reinterpret_cast<const int4*>(&bp[i]);
            stage[i]     = make_int2(p.x, p.y);
            stage[i + 1] = make_int2(p.z, p.w);
            atomicAdd(&hist[(p.x >> 17) & (BROWS - 1)], 1);
            atomicAdd(&hist[(p.z >> 17) & (BROWS - 1)], 1);
        } else {
            const int2 e = bp[i];
            stage[i] = e;
            atomicAdd(&hist[(e.x >> 17) & (BROWS - 1)], 1);
        }
    }
    __syncthreads();

    // Hillis-Steele inclusive scan over 128 counters
    if (tid < BROWS) base[tid] = hist[tid];
    __syncthreads();
    for (int d = 1; d < BROWS; d <<= 1) {
        int v = 0;
        if (tid < BROWS && tid >= d) v = base[tid - d];
        __syncthreads();
        if (tid < BROWS) base[tid] += v;
        __syncthreads();
    }
    if (tid < BROWS) {
        const int ex = base[tid] - hist[tid];   // exclusive
        cur[tid] = ex;
        const int row = (bin << 7) + tid;
        if (row < N) srow[row] = make_int2(bin * BCAP + ex, hist[tid]);
    }
    __syncthreads();

    // scatter back row-sorted, strip row bits
    for (int i = tid; i < cnt; i += 256) {
        const int2 e = stage[i];
        const int  r = (e.x >> 17) & (BROWS - 1);
        const int  pos = atomicAdd(&cur[r], 1);
        bp[pos] = make_int2(e.x & 0x1FFFF, e.y);
    }
}

// ===========================================================================
// Gather: one wave per row, PAIR-LANE layout: lanes 0-31 = even edges,
// lanes 32-63 = odd edges; each lane covers 2 features via one half2 load.
// Unroll 8 loads/lane = 16 edges in flight per wave (2x R8's MLP).
// Fold halves with shfl_xor(32); lanes 0-31 write float2. PReLU fused.
// ===========================================================================
__global__ __launch_bounds__(256) void k_gather(
    const __half* __restrict__ h, const int2* __restrict__ srow,
    const int2* __restrict__ ebuf, const float* __restrict__ alpha,
    float* __restrict__ out, int N)
{
    const int wid  = (int)((blockIdx.x * (size_t)blockDim.x + threadIdx.x) >> 6);
    const int lane = threadIdx.x & 63;
    if (wid >= N) return;

    const int2 sd   = srow[wid];
    const int start = sd.x;
    const int deg   = sd.y;

    const int half_id = lane >> 5;    // 0: even edge of pair, 1: odd edge
    const int fl      = lane & 31;    // feature pair: features 2fl, 2fl+1

    float ax = 0.f, ay = 0.f;
    int j = 0;
    // 8 pairs = 16 edges per iteration
    for (; j + 16 <= deg; j += 16) {
        int2 cv[8];
#pragma unroll
        for (int u = 0; u < 8; ++u) cv[u] = ebuf[start + j + 2 * u + half_id];
        __half2 hv[8];
#pragma unroll
        for (int u = 0; u < 8; ++u)
            hv[u] = *reinterpret_cast<const __half2*>(
                        &h[(size_t)cv[u].x * OUT_FT + 2 * fl]);
#pragma unroll
        for (int u = 0; u < 8; ++u) {
            const float  v = __int_as_float(cv[u].y);
            const float2 f = __half22float2(hv[u]);
            ax += v * f.x;  ay += v * f.y;
        }
    }
    // 4 pairs = 8 edges
    if (j + 8 <= deg) {
        int2 cv[4];
#pragma unroll
        for (int u = 0; u < 4; ++u) cv[u] = ebuf[start + j + 2 * u + half_id];
        __half2 hv[4];
#pragma unroll
        for (int u = 0; u < 4; ++u)
            hv[u] = *reinterpret_cast<const __half2*>(
                        &h[(size_t)cv[u].x * OUT_FT + 2 * fl]);
#pragma unroll
        for (int u = 0; u < 4; ++u) {
            const float  v = __int_as_float(cv[u].y);
            const float2 f = __half22float2(hv[u]);
            ax += v * f.x;  ay += v * f.y;
        }
        j += 8;
    }
    // single pairs (2 edges)
    for (; j + 2 <= deg; j += 2) {
        const int2 cv = ebuf[start + j + half_id];
        const float2 f = __half22float2(*reinterpret_cast<const __half2*>(
                             &h[(size_t)cv.x * OUT_FT + 2 * fl]));
        const float v = __int_as_float(cv.y);
        ax += v * f.x;  ay += v * f.y;
    }
    // final odd edge: half 0 only
    if (j < deg && half_id == 0) {
        const int2 cv = ebuf[start + j];
        const float2 f = __half22float2(*reinterpret_cast<const __half2*>(
                             &h[(size_t)cv.x * OUT_FT + 2 * fl]));
        const float v = __int_as_float(cv.y);
        ax += v * f.x;  ay += v * f.y;
    }

    // fold the two half-wave partials
    ax += __shfl_xor(ax, 32);
    ay += __shfl_xor(ay, 32);

    if (half_id == 0) {
        const float a = alpha[0];
        float2 o;
        o.x = ax >= 0.f ? ax : a * ax;
        o.y = ay >= 0.f ? ay : a * ay;
        *reinterpret_cast<float2*>(&out[(size_t)wid * OUT_FT + 2 * fl]) = o;
    }
}

// ===========================================================================
// Fallback path (ws too small / N too large for 17-bit col pack)
// ===========================================================================
__global__ __launch_bounds__(256) void gcn_fc_kernel(
    const float* __restrict__ x, const float* __restrict__ W,
    const float* __restrict__ b, float* __restrict__ h, int N)
{
    __shared__ float Wl[IN_FT * OUT_FT];
    __shared__ float xs[ROWS_PER_BLOCK * XS_STRIDE];

    const int tid  = threadIdx.x;
    const int row0 = blockIdx.x * ROWS_PER_BLOCK;

    for (int i = tid; i < (IN_FT * OUT_FT) / 4; i += 256)
        reinterpret_cast<float4*>(Wl)[i] = reinterpret_cast<const float4*>(W)[i];

    for (int i = tid; i < (ROWS_PER_BLOCK * IN_FT) / 4; i += 256) {
        const int r  = i / (IN_FT / 4);
        const int c4 = i % (IN_FT / 4);
        float4 v = make_float4(0.f, 0.f, 0.f, 0.f);
        if (row0 + r < N)
            v = reinterpret_cast<const float4*>(x + (size_t)(row0 + r) * IN_FT)[c4];
        reinterpret_cast<float4*>(&xs[r * XS_STRIDE])[c4] = v;
    }
    __syncthreads();

    const int jg = tid & 15;
    const int rg = tid >> 4;

    const float4 bv = reinterpret_cast<const float4*>(b)[jg];
    float acc[4][4];
#pragma unroll
    for (int rr = 0; rr < 4; ++rr) {
        acc[rr][0] = bv.x; acc[rr][1] = bv.y; acc[rr][2] = bv.z; acc[rr][3] = bv.w;
    }

    for (int k0 = 0; k0 < IN_FT; k0 += 4) {
        float wf[4][4];
#pragma unroll
        for (int kk = 0; kk < 4; ++kk) {
            const float4 t = *reinterpret_cast<const float4*>(&Wl[(k0 + kk) * OUT_FT + 4 * jg]);
            wf[kk][0] = t.x; wf[kk][1] = t.y; wf[kk][2] = t.z; wf[kk][3] = t.w;
        }
#pragma unroll
        for (int rr = 0; rr < 4; ++rr) {
            const float4 xv = *reinterpret_cast<const float4*>(&xs[(4 * rg + rr) * XS_STRIDE + k0]);
            const float xk[4] = {xv.x, xv.y, xv.z, xv.w};
#pragma unroll
            for (int kk = 0; kk < 4; ++kk)
#pragma unroll
                for (int jj = 0; jj < 4; ++jj)
                    acc[rr][jj] += xk[kk] * wf[kk][jj];
        }
    }

#pragma unroll
    for (int rr = 0; rr < 4; ++rr) {
        const int r = row0 + 4 * rg + rr;
        if (r < N)
            *reinterpret_cast<float4*>(&h[(size_t)r * OUT_FT + 4 * jg]) =
                make_float4(acc[rr][0], acc[rr][1], acc[rr][2], acc[rr][3]);
    }
}

__global__ __launch_bounds__(256) void gcn_scatter_kernel(
    const float* __restrict__ h, const int* __restrict__ erow,
    const int* __restrict__ ecol, const float* __restrict__ eval_,
    float* __restrict__ out, int E)
{
    const int t  = blockIdx.x * blockDim.x + threadIdx.x;
    const int e  = t >> 4;
    const int fg = (t & 15) * 4;
    if (e >= E) return;
    const int   col = ecol[e];
    const int   row = erow[e];
    const float v   = eval_[e];
    const float4 hv = *reinterpret_cast<const float4*>(&h[(size_t)col * OUT_FT + fg]);
    float* op = &out[(size_t)row * OUT_FT + fg];
    atomicAdd(op + 0, v * hv.x);
    atomicAdd(op + 1, v * hv.y);
    atomicAdd(op + 2, v * hv.z);
    atomicAdd(op + 3, v * hv.w);
}

__global__ __launch_bounds__(256) void gcn_prelu_kernel(
    float* __restrict__ out, const float* __restrict__ alpha, int n4)
{
    const float a = alpha[0];
    for (int i = blockIdx.x * blockDim.x + threadIdx.x; i < n4;
         i += gridDim.x * blockDim.x) {
        float4 v = reinterpret_cast<float4*>(out)[i];
        v.x = v.x >= 0.f ? v.x : a * v.x;
        v.y = v.y >= 0.f ? v.y : a * v.y;
        v.z = v.z >= 0.f ? v.z : a * v.z;
        v.w = v.w >= 0.f ? v.w : a * v.w;
        reinterpret_cast<float4*>(out)[i] = v;
    }
}

// ===========================================================================
extern "C" void kernel_launch(void* const* d_in, const int* in_sizes, int n_in,
                              void* d_out, int out_size, void* d_ws, size_t ws_size,
                              hipStream_t stream)
{
    const float* x     = (const float*)d_in[0];
    const float* W     = (const float*)d_in[1];
    const float* b     = (const float*)d_in[2];
    const float* alpha = (const float*)d_in[3];
    const int*   erow  = (const int*)d_in[4];
    const int*   ecol  = (const int*)d_in[5];
    const float* eval_ = (const float*)d_in[6];
    float* out = (float*)d_out;

    const int N = in_sizes[0] / IN_FT;   // 100000
    const int E = in_sizes[4];           // 1600000
    const int NB = (N + BROWS - 1) / BROWS;   // 782 buckets

    // ---- workspace: gcur | ebuf | srow | h fp16  (~30 MB) ----
    auto al16 = [](size_t v) { return (v + 15) & ~15ull; };
    char* ws = (char*)d_ws;

    size_t off = 0;
    int*    gcur = (int*)(ws + off);   off += al16((size_t)NB * sizeof(int));
    int2*   ebuf = (int2*)(ws + off);  off += al16((size_t)NB * BCAP * sizeof(int2));
    int2*   srow = (int2*)(ws + off);  off += al16((size_t)N * sizeof(int2));
    __half* h16  = (__half*)(ws + off); off += al16((size_t)N * OUT_FT * sizeof(__half));

    const bool fast_ok = (off <= ws_size) && (NB <= 1024) && (N <= (1 << 17));

    if (fast_ok) {
        hipMemsetAsync(gcur, 0, (size_t)NB * sizeof(int), stream);
        k_partition<<<PART_BLOCKS, 256, 0, stream>>>(
            erow, ecol, eval_, gcur, ebuf, E, NB);
        k_localcsr<<<NB, 256, 0, stream>>>(gcur, ebuf, srow, N);
        gcn_fc_fp16_kernel<<<(N + ROWS_PER_BLOCK - 1) / ROWS_PER_BLOCK, 256, 0, stream>>>(
            x, W, b, h16, N);
        const size_t gthreads = (size_t)N * 64;
        k_gather<<<(int)((gthreads + 255) / 256), 256, 0, stream>>>(
            h16, srow, ebuf, alpha, out, N);
    } else {
        float* hf = (float*)ws;
        gcn_fc_kernel<<<(N + ROWS_PER_BLOCK - 1) / ROWS_PER_BLOCK, 256, 0, stream>>>(
            x, W, b, hf, N);
        hipMemsetAsync(d_out, 0, (size_t)N * OUT_FT * sizeof(float), stream);
        const long long st = (long long)E * 16;
        gcn_scatter_kernel<<<(st + 255) / 256, 256, 0, stream>>>(
            hf, erow, ecol, eval_, out, E);
        gcn_prelu_kernel<<<2048, 256, 0, stream>>>(out, alpha, (N * OUT_FT) / 4);
    }
}